// Round 5
// baseline (317.524 us; speedup 1.0000x reference)
//
#include <hip/hip_runtime.h>
#include <hip/hip_bf16.h>
#include <stdint.h>

typedef short bf16x8 __attribute__((ext_vector_type(8)));
typedef float f32x4  __attribute__((ext_vector_type(4)));
typedef int   i32x4  __attribute__((ext_vector_type(4)));

#define NB   8
#define NC   256
#define NO   256
#define HH   64
#define WW   64
#define NPIX 4096
#define KTOT 2304
#define NKC  72

// workspace layout (bytes)
#define XN_OFF  0u
#define XN_SZ   (NB*NPIX*NC*2u)
#define WP_OFF  (XN_OFF + XN_SZ)
#define WP_SZ   (KTOT*NO*2u)
#define WPO_OFF (WP_OFF + WP_SZ)
#define WPO_SZ  (KTOT*32u*2u)
#define OM_OFF  (WPO_OFF + WPO_SZ)
#define OM_SZ   (NB*NPIX*32u*4u)
#define PY_OFF  (OM_OFF + OM_SZ)
#define CO_SZ   (NB*9u*NPIX*4u)
#define PX_OFF  (PY_OFF + CO_SZ)
#define MK_OFF  (PX_OFF + CO_SZ)

__device__ __forceinline__ float b2f(short s) {
    union { unsigned u; float f; } z; z.u = ((unsigned)(unsigned short)s) << 16; return z.f;
}
__device__ __forceinline__ short f2b(float f) {
    __hip_bfloat16 h = __float2bfloat16(f);
    short s; __builtin_memcpy(&s, &h, 2); return s;
}
__device__ __forceinline__ float dw_lo(int u) {
    union { int i; float f; } z; z.i = u << 16; return z.f;
}
__device__ __forceinline__ float dw_hi(int u) {
    union { int i; float f; } z; z.i = u & 0xFFFF0000; return z.f;
}

// blend 4 corner bf16x8 vectors with weights -> bf16x8 (RNE via v_cvt_pk_bf16_f32)
__device__ __forceinline__ bf16x8 blend4(bf16x8 c0, bf16x8 c1, bf16x8 c2, bf16x8 c3,
                                         float w0, float w1, float w2, float w3) {
    union U { bf16x8 s; i32x4 i; } u0, u1, u2, u3, r;
    u0.s = c0; u1.s = c1; u2.s = c2; u3.s = c3;
#pragma unroll
    for (int d = 0; d < 4; ++d) {
        float lo = w0*dw_lo(u0.i[d]) + w1*dw_lo(u1.i[d]) + w2*dw_lo(u2.i[d]) + w3*dw_lo(u3.i[d]);
        float hi = w0*dw_hi(u0.i[d]) + w1*dw_hi(u1.i[d]) + w2*dw_hi(u2.i[d]) + w3*dw_hi(u3.i[d]);
        int pk;
        asm("v_cvt_pk_bf16_f32 %0, %1, %2" : "=v"(pk) : "v"(lo), "v"(hi));
        r.i[d] = pk;
    }
    return r.s;
}

// ---------------- kernel 1: x (NCHW f32) -> xn (NHWC bf16), vectorized ----------------
__global__ void pack_x(const float* __restrict__ x, unsigned short* __restrict__ xn) {
    __shared__ float tile[64][65];
    int blk = blockIdx.x;                  // 2048 = 8b * 4ct * 64pt
    int pt = blk & 63, ct = (blk >> 6) & 3, b = blk >> 8;
    int t = threadIdx.x;
    int ci = t >> 4, p4 = (t & 15) * 4;
    const float* src = x + ((size_t)(b*NC + ct*64))*NPIX + (size_t)pt*64;
#pragma unroll
    for (int j = 0; j < 4; ++j) {
        f32x4 v = *(const f32x4*)(src + (size_t)(ci + 16*j)*NPIX + p4);
        tile[ci + 16*j][p4+0] = v[0];
        tile[ci + 16*j][p4+1] = v[1];
        tile[ci + 16*j][p4+2] = v[2];
        tile[ci + 16*j][p4+3] = v[3];
    }
    __syncthreads();
    int c8 = (t & 7) * 8, pj0 = t >> 3;
    unsigned short* dst = xn + ((size_t)b*NPIX + (size_t)pt*64)*NC + ct*64 + c8;
#pragma unroll
    for (int j = 0; j < 2; ++j) {
        int pj = pj0 + 32*j;
        bf16x8 o;
#pragma unroll
        for (int e = 0; e < 8; ++e) o[e] = f2b(tile[c8 + e][pj]);
        *(bf16x8*)(dst + (size_t)pj*NC) = o;
    }
}

// ---------------- kernel 2: pack main weight into B-fragment order ----------------
// flat = ((kc*16 + nt)*64 + l)*8 + e ; value = W[k][o], k = kc*32 + 8*(l>>4) + e
__global__ void pack_w(const float* __restrict__ weight, unsigned short* __restrict__ wp) {
    int idx = blockIdx.x*256 + threadIdx.x;
    int e = idx & 7, l = (idx >> 3) & 63, nt = (idx >> 9) & 15, kc = idx >> 13;
    int k  = kc*32 + 8*(l >> 4) + e;
    int k2 = k >> 8, c = k & 255;
    int ky = k2 / 3, kx = k2 - 3*ky;
    int o  = nt*16 + (l & 15);
    float v = weight[(size_t)(o*NC + c)*9 + ky*3 + kx];
    wp[idx] = (unsigned short)f2b(v);
}

// ---------------- kernel 3: pack offset-conv weight (N padded 27->32) ----------------
__global__ void pack_wo(const float* __restrict__ w_off, unsigned short* __restrict__ wpo) {
    int idx = blockIdx.x*256 + threadIdx.x;
    int e = idx & 7, l = (idx >> 3) & 63, nt = (idx >> 9) & 1, kc = idx >> 10;
    int k  = kc*32 + 8*(l >> 4) + e;
    int k2 = k >> 8, c = k & 255;
    int ky = k2 / 3, kx = k2 - 3*ky;
    int n  = nt*16 + (l & 15);
    float v = (n < 27) ? w_off[(size_t)(n*NC + c)*9 + ky*3 + kx] : 0.0f;
    wpo[idx] = (unsigned short)f2b(v);
}

// ---------------- kernel 4: offset conv — 1 frag/wave, 4096 waves, no LDS/barriers ---
__launch_bounds__(256, 4)
__global__ void off_conv(const unsigned short* __restrict__ xn,
                         const unsigned short* __restrict__ wpo,
                         float* __restrict__ om) {
    int bid = blockIdx.x;                 // 1024 = 8 batches x 128
    int b = bid & 7, rr = bid >> 3;       // rr 0..127
    int t = threadIdx.x, wv = t >> 6, l = t & 63, g = l >> 4, l15 = l & 15;
    int wid = rr*4 + wv;                  // 0..511
    int mt = wid >> 1, nh = wid & 1;      // mt 0..255 (16 pix), nh half of N=32
    int pix = mt*16 + l15;
    int y = pix >> 6, xx = pix & 63;
    f32x4 acc = {0.f,0.f,0.f,0.f};
    const char* xc = (const char*)(xn + (size_t)b*NPIX*NC);
    const bf16x8* wpf = (const bf16x8*)wpo;
    const bf16x8 zero8 = {0,0,0,0,0,0,0,0};
#pragma unroll
    for (int kc = 0; kc < NKC; ++kc) {
        int k2 = kc >> 3, cc = kc & 7;
        int ky = k2 / 3, kx = k2 - 3*ky;
        int sy = y + ky - 1, sx = xx + kx - 1;
        bool valid = (sy>=0)&(sy<HH)&(sx>=0)&(sx<WW);
        int cs = min(max(sy,0),HH-1)*WW + min(max(sx,0),WW-1);
        bf16x8 a = *(const bf16x8*)(xc + ((size_t)cs*NC + cc*32 + g*8)*2);
        bf16x8 w = wpf[(size_t)(kc*2 + nh)*64 + l];
        acc = __builtin_amdgcn_mfma_f32_16x16x32_bf16(valid ? a : zero8, w, acc, 0, 0, 0);
    }
#pragma unroll
    for (int r = 0; r < 4; ++r) {
        int pm = mt*16 + 4*g + r;
        om[((size_t)b*NPIX + pm)*32 + nh*16 + l15] = acc[r];
    }
}

// ---------------- kernel 5: om -> sampling coords (py, px, mask) ----------------
__global__ void coords_k(const float* __restrict__ om, const float* __restrict__ b_off,
                         float* __restrict__ py, float* __restrict__ px,
                         float* __restrict__ mk) {
    int idx = blockIdx.x*256 + threadIdx.x;
    if (idx >= NB*9*NPIX) return;
    int pix = idx & 4095;
    int k   = (idx >> 12) % 9;
    int b   = idx / (9*NPIX);
    const float* omp = om + ((size_t)b*NPIX + pix)*32;
    float dy = omp[2*k]     + b_off[2*k];
    float dx = omp[2*k + 1] + b_off[2*k + 1];
    float m  = omp[18 + k]  + b_off[18 + k];
    float yy = (float)(pix >> 6) - 1.0f + (float)(k / 3) + dy;
    float xv = (float)(pix & 63) - 1.0f + (float)(k % 3) + dx;
    py[idx] = yy;
    px[idx] = xv;
    mk[idx] = 1.0f / (1.0f + __expf(-m));
}

// ---------------- kernel 6: main deformable conv — K-split across waves -------------
// 2048 blocks = 8 b x 128 mt x 2 nh. Block: 4 waves, ALL over the same output tile
// M=32 (2 A-frags) x N=128 (8 W-frags); wave wv owns K-quarter [wv*576,(wv+1)*576).
// NO LDS / NO barriers in the main loop; W-frags read straight from L2 (batch+W fit
// a 4MB XCD L2); 4-barrier LDS tree-reduce at the end combines the K-quarters.
#define RST 132          // padded row stride (f32) for reduce buffer
__launch_bounds__(256, 3)
__global__ void dcn_main(const unsigned short* __restrict__ xn,
                         const unsigned short* __restrict__ wpack,
                         const float* __restrict__ pyA,
                         const float* __restrict__ pxA,
                         const float* __restrict__ mkA,
                         const float* __restrict__ bias,
                         float* __restrict__ out) {
    __shared__ float red[2][32*RST];              // 2 x 16.9 KB
    int bid = blockIdx.x;
    int b  = bid & 7;                             // batch per XCD
    int u  = bid >> 3;                            // 0..255
    int nh = u & 1, mt = u >> 1;                  // N-half, M-tile 0..127
    int t = threadIdx.x, l = t & 63, g = l >> 4, l15 = l & 15;
    int wv = __builtin_amdgcn_readfirstlane(t >> 6);   // K-quarter (scalar)
    int pix0 = mt*32 + l15;                       // frag f adds +f*16

    f32x4 acc[2][8];
#pragma unroll
    for (int f = 0; f < 2; ++f)
#pragma unroll
        for (int nt = 0; nt < 8; ++nt) acc[f][nt] = f32x4{0.f,0.f,0.f,0.f};

    const char* xc = (const char*)(xn + (size_t)b*NPIX*NC);

    float cw[2][4];
    unsigned co[2][4];                            // corner byte offsets into xc

    auto coord_compute = [&](int k2) {
#pragma unroll
        for (int f = 0; f < 2; ++f) {
            int ci = ((b*9 + k2) << 12) + pix0 + f*16;
            float py = pyA[ci], px = pxA[ci], m = mkA[ci];
            float y0f = floorf(py), x0f = floorf(px);
            float ly = py - y0f, lx = px - x0f;
            int iy0 = (int)y0f, ix0 = (int)x0f;
            int iy1 = iy0 + 1,  ix1 = ix0 + 1;
            bool vy0 = (iy0 >= 0) & (iy0 < HH);
            bool vy1 = (iy1 >= 0) & (iy1 < HH);
            bool vx0 = (ix0 >= 0) & (ix0 < WW);
            bool vx1 = (ix1 >= 0) & (ix1 < WW);
            float wy0 = (1.f - ly) * m, wy1 = ly * m;
            cw[f][0] = (vy0 & vx0) ? wy0 * (1.f - lx) : 0.f;
            cw[f][1] = (vy0 & vx1) ? wy0 * lx         : 0.f;
            cw[f][2] = (vy1 & vx0) ? wy1 * (1.f - lx) : 0.f;
            cw[f][3] = (vy1 & vx1) ? wy1 * lx         : 0.f;
            int cy0 = min(max(iy0,0),HH-1), cy1 = min(max(iy1,0),HH-1);
            int cx0 = min(max(ix0,0),WW-1), cx1 = min(max(ix1,0),WW-1);
            co[f][0] = (unsigned)(((cy0*WW + cx0)*NC + g*8) * 2);
            co[f][1] = (unsigned)(((cy0*WW + cx1)*NC + g*8) * 2);
            co[f][2] = (unsigned)(((cy1*WW + cx0)*NC + g*8) * 2);
            co[f][3] = (unsigned)(((cy1*WW + cx1)*NC + g*8) * 2);
        }
    };

    {
        int kcg0 = wv*18;
        coord_compute(kcg0 >> 3);
    }
#pragma unroll
    for (int tt = 0; tt < 18; ++tt) {
        int kcg = wv*18 + tt;                     // scalar
        int k2 = kcg >> 3, cc = kcg & 7;
        if (tt > 0 && cc == 0) coord_compute(k2); // scalar branch
        unsigned cb = (unsigned)cc * 64u;
        // 8 W-frags straight from global (L2-resident)
        const bf16x8* wf = (const bf16x8*)wpack + ((size_t)kcg*16 + nh*8)*64 + l;
        bf16x8 af[2];
#pragma unroll
        for (int f = 0; f < 2; ++f) {
            bf16x8 c0 = *(const bf16x8*)(xc + co[f][0] + cb);
            bf16x8 c1 = *(const bf16x8*)(xc + co[f][1] + cb);
            bf16x8 c2 = *(const bf16x8*)(xc + co[f][2] + cb);
            bf16x8 c3 = *(const bf16x8*)(xc + co[f][3] + cb);
            af[f] = blend4(c0, c1, c2, c3, cw[f][0], cw[f][1], cw[f][2], cw[f][3]);
        }
#pragma unroll
        for (int nt = 0; nt < 8; ++nt) {
            bf16x8 w = wf[nt*64];
            acc[0][nt] = __builtin_amdgcn_mfma_f32_16x16x32_bf16(af[0], w, acc[0][nt], 0, 0, 0);
            acc[1][nt] = __builtin_amdgcn_mfma_f32_16x16x32_bf16(af[1], w, acc[1][nt], 0, 0, 0);
        }
    }

    // ---- cross-wave K reduction via LDS (only barriers in the kernel) ----
    // element (f,nt,r) lives at row = f*16+4g+r (0..31), col = nt*16+l15 (0..127)
    __syncthreads();
    if (wv >= 2) {
        float* s = red[wv - 2];
#pragma unroll
        for (int f = 0; f < 2; ++f)
#pragma unroll
            for (int nt = 0; nt < 8; ++nt)
#pragma unroll
                for (int r = 0; r < 4; ++r)
                    s[(f*16 + 4*g + r)*RST + nt*16 + l15] = acc[f][nt][r];
    }
    __syncthreads();
    if (wv < 2) {
        const float* s = red[wv];
#pragma unroll
        for (int f = 0; f < 2; ++f)
#pragma unroll
            for (int nt = 0; nt < 8; ++nt)
#pragma unroll
                for (int r = 0; r < 4; ++r)
                    acc[f][nt][r] += s[(f*16 + 4*g + r)*RST + nt*16 + l15];
    }
    __syncthreads();
    if (wv == 1) {
        float* s = red[0];
#pragma unroll
        for (int f = 0; f < 2; ++f)
#pragma unroll
            for (int nt = 0; nt < 8; ++nt)
#pragma unroll
                for (int r = 0; r < 4; ++r)
                    s[(f*16 + 4*g + r)*RST + nt*16 + l15] = acc[f][nt][r];
    }
    __syncthreads();
    if (wv == 0) {
        const float* s = red[0];
#pragma unroll
        for (int f = 0; f < 2; ++f)
#pragma unroll
            for (int nt = 0; nt < 8; ++nt) {
                int o = nh*128 + nt*16 + l15;
                float bv = bias[o];
                f32x4 r = acc[f][nt];
#pragma unroll
                for (int rr = 0; rr < 4; ++rr)
                    r[rr] += s[(f*16 + 4*g + rr)*RST + nt*16 + l15] + bv;
                *(f32x4*)(out + ((size_t)(b*NO + o))*NPIX + mt*32 + f*16 + 4*g) = r;
            }
    }
}

extern "C" void kernel_launch(void* const* d_in, const int* in_sizes, int n_in,
                              void* d_out, int out_size, void* d_ws, size_t ws_size,
                              hipStream_t stream) {
    const float* x      = (const float*)d_in[0];
    const float* weight = (const float*)d_in[1];
    const float* bias   = (const float*)d_in[2];
    const float* w_off  = (const float*)d_in[3];
    const float* b_off  = (const float*)d_in[4];
    float* out = (float*)d_out;
    char* ws = (char*)d_ws;

    unsigned short* xn  = (unsigned short*)(ws + XN_OFF);
    unsigned short* wp  = (unsigned short*)(ws + WP_OFF);
    unsigned short* wpo = (unsigned short*)(ws + WPO_OFF);
    float* om = (float*)(ws + OM_OFF);
    float* py = (float*)(ws + PY_OFF);
    float* px = (float*)(ws + PX_OFF);
    float* mk = (float*)(ws + MK_OFF);

    pack_x  <<<2048, 256, 0, stream>>>(x, xn);
    pack_w  <<<KTOT*NO/256,  256, 0, stream>>>(weight, wp);
    pack_wo <<<KTOT*32/256,  256, 0, stream>>>(w_off, wpo);
    off_conv<<<1024, 256, 0, stream>>>(xn, wpo, om);
    coords_k<<<NB*9*NPIX/256, 256, 0, stream>>>(om, b_off, py, px, mk);
    dcn_main<<<2048, 256, 0, stream>>>(xn, wp, py, px, mk, bias, out);
}

// Round 6
// 250.935 us; speedup vs baseline: 1.2654x; 1.2654x over previous
//
#include <hip/hip_runtime.h>
#include <hip/hip_bf16.h>
#include <stdint.h>

typedef short bf16x8 __attribute__((ext_vector_type(8)));
typedef float f32x4  __attribute__((ext_vector_type(4)));
typedef int   i32x4  __attribute__((ext_vector_type(4)));

#define NB   8
#define NC   256
#define NO   256
#define HH   64
#define WW   64
#define NPIX 4096
#define KTOT 2304
#define NKC  72
#define NMF  2048           // total M-fragments (32768 pixels / 16)

// workspace layout (bytes)
#define XN_OFF  0u
#define XN_SZ   (NB*NPIX*NC*2u)
#define WP_OFF  (XN_OFF + XN_SZ)
#define WP_SZ   (KTOT*NO*2u)
#define WPO_OFF (WP_OFF + WP_SZ)
#define WPO_SZ  (KTOT*32u*2u)
#define OM_OFF  (WPO_OFF + WPO_SZ)
#define OM_SZ   (NB*NPIX*32u*4u)
#define PY_OFF  (OM_OFF + OM_SZ)
#define CO_SZ   (NB*9u*NPIX*4u)
#define PX_OFF  (PY_OFF + CO_SZ)
#define MK_OFF  (PX_OFF + CO_SZ)
#define AM_OFF  (MK_OFF + CO_SZ)                    // 25,837,568
#define AM_SZ   ((size_t)NKC*NMF*1024ull)           // 150,994,944

__device__ __forceinline__ float b2f(short s) {
    union { unsigned u; float f; } z; z.u = ((unsigned)(unsigned short)s) << 16; return z.f;
}
__device__ __forceinline__ short f2b(float f) {
    __hip_bfloat16 h = __float2bfloat16(f);
    short s; __builtin_memcpy(&s, &h, 2); return s;
}
__device__ __forceinline__ float dw_lo(int u) {
    union { int i; float f; } z; z.i = u << 16; return z.f;
}
__device__ __forceinline__ float dw_hi(int u) {
    union { int i; float f; } z; z.i = u & 0xFFFF0000; return z.f;
}

__device__ __forceinline__ bf16x8 blend4(bf16x8 c0, bf16x8 c1, bf16x8 c2, bf16x8 c3,
                                         float w0, float w1, float w2, float w3) {
    union U { bf16x8 s; i32x4 i; } u0, u1, u2, u3, r;
    u0.s = c0; u1.s = c1; u2.s = c2; u3.s = c3;
#pragma unroll
    for (int d = 0; d < 4; ++d) {
        float lo = w0*dw_lo(u0.i[d]) + w1*dw_lo(u1.i[d]) + w2*dw_lo(u2.i[d]) + w3*dw_lo(u3.i[d]);
        float hi = w0*dw_hi(u0.i[d]) + w1*dw_hi(u1.i[d]) + w2*dw_hi(u2.i[d]) + w3*dw_hi(u3.i[d]);
        int pk;
        asm("v_cvt_pk_bf16_f32 %0, %1, %2" : "=v"(pk) : "v"(lo), "v"(hi));
        r.i[d] = pk;
    }
    return r.s;
}

// ---------------- kernel 1: x (NCHW f32) -> xn (NHWC bf16) ----------------
__global__ void pack_x(const float* __restrict__ x, unsigned short* __restrict__ xn) {
    __shared__ float tile[64][65];
    int blk = blockIdx.x;
    int pt = blk & 63, ct = (blk >> 6) & 3, b = blk >> 8;
    int t = threadIdx.x;
    int ci = t >> 4, p4 = (t & 15) * 4;
    const float* src = x + ((size_t)(b*NC + ct*64))*NPIX + (size_t)pt*64;
#pragma unroll
    for (int j = 0; j < 4; ++j) {
        f32x4 v = *(const f32x4*)(src + (size_t)(ci + 16*j)*NPIX + p4);
        tile[ci + 16*j][p4+0] = v[0];
        tile[ci + 16*j][p4+1] = v[1];
        tile[ci + 16*j][p4+2] = v[2];
        tile[ci + 16*j][p4+3] = v[3];
    }
    __syncthreads();
    int c8 = (t & 7) * 8, pj0 = t >> 3;
    unsigned short* dst = xn + ((size_t)b*NPIX + (size_t)pt*64)*NC + ct*64 + c8;
#pragma unroll
    for (int j = 0; j < 2; ++j) {
        int pj = pj0 + 32*j;
        bf16x8 o;
#pragma unroll
        for (int e = 0; e < 8; ++e) o[e] = f2b(tile[c8 + e][pj]);
        *(bf16x8*)(dst + (size_t)pj*NC) = o;
    }
}

// ---------------- kernel 2: pack main weight into B-fragment order ----------------
__global__ void pack_w(const float* __restrict__ weight, unsigned short* __restrict__ wp) {
    int idx = blockIdx.x*256 + threadIdx.x;
    int e = idx & 7, l = (idx >> 3) & 63, nt = (idx >> 9) & 15, kc = idx >> 13;
    int k  = kc*32 + 8*(l >> 4) + e;
    int k2 = k >> 8, c = k & 255;
    int ky = k2 / 3, kx = k2 - 3*ky;
    int o  = nt*16 + (l & 15);
    float v = weight[(size_t)(o*NC + c)*9 + ky*3 + kx];
    wp[idx] = (unsigned short)f2b(v);
}

// ---------------- kernel 3: pack offset-conv weight (N padded 27->32) ----------------
__global__ void pack_wo(const float* __restrict__ w_off, unsigned short* __restrict__ wpo) {
    int idx = blockIdx.x*256 + threadIdx.x;
    int e = idx & 7, l = (idx >> 3) & 63, nt = (idx >> 9) & 1, kc = idx >> 10;
    int k  = kc*32 + 8*(l >> 4) + e;
    int k2 = k >> 8, c = k & 255;
    int ky = k2 / 3, kx = k2 - 3*ky;
    int n  = nt*16 + (l & 15);
    float v = (n < 27) ? w_off[(size_t)(n*NC + c)*9 + ky*3 + kx] : 0.0f;
    wpo[idx] = (unsigned short)f2b(v);
}

// ---------------- kernel 4: offset conv — 1 frag/wave, no LDS/barriers ----------------
__launch_bounds__(256, 4)
__global__ void off_conv(const unsigned short* __restrict__ xn,
                         const unsigned short* __restrict__ wpo,
                         float* __restrict__ om) {
    int bid = blockIdx.x;                 // 1024 = 8 batches x 128
    int b = bid & 7, rr = bid >> 3;
    int t = threadIdx.x, wv = t >> 6, l = t & 63, g = l >> 4, l15 = l & 15;
    int wid = rr*4 + wv;
    int mt = wid >> 1, nh = wid & 1;
    int pix = mt*16 + l15;
    int y = pix >> 6, xx = pix & 63;
    f32x4 acc = {0.f,0.f,0.f,0.f};
    const char* xc = (const char*)(xn + (size_t)b*NPIX*NC);
    const bf16x8* wpf = (const bf16x8*)wpo;
    const bf16x8 zero8 = {0,0,0,0,0,0,0,0};
#pragma unroll
    for (int kc = 0; kc < NKC; ++kc) {
        int k2 = kc >> 3, cc = kc & 7;
        int ky = k2 / 3, kx = k2 - 3*ky;
        int sy = y + ky - 1, sx = xx + kx - 1;
        bool valid = (sy>=0)&(sy<HH)&(sx>=0)&(sx<WW);
        int cs = min(max(sy,0),HH-1)*WW + min(max(sx,0),WW-1);
        bf16x8 a = *(const bf16x8*)(xc + ((size_t)cs*NC + cc*32 + g*8)*2);
        bf16x8 w = wpf[(size_t)(kc*2 + nh)*64 + l];
        acc = __builtin_amdgcn_mfma_f32_16x16x32_bf16(valid ? a : zero8, w, acc, 0, 0, 0);
    }
#pragma unroll
    for (int r = 0; r < 4; ++r) {
        int pm = mt*16 + 4*g + r;
        om[((size_t)b*NPIX + pm)*32 + nh*16 + l15] = acc[r];
    }
}

// ---------------- kernel 5: om -> sampling coords (py, px, mask) ----------------
__global__ void coords_k(const float* __restrict__ om, const float* __restrict__ b_off,
                         float* __restrict__ py, float* __restrict__ px,
                         float* __restrict__ mk) {
    int idx = blockIdx.x*256 + threadIdx.x;
    if (idx >= NB*9*NPIX) return;
    int pix = idx & 4095;
    int k   = (idx >> 12) % 9;
    int b   = idx / (9*NPIX);
    const float* omp = om + ((size_t)b*NPIX + pix)*32;
    float dy = omp[2*k]     + b_off[2*k];
    float dx = omp[2*k + 1] + b_off[2*k + 1];
    float m  = omp[18 + k]  + b_off[18 + k];
    float yy = (float)(pix >> 6) - 1.0f + (float)(k / 3) + dy;
    float xv = (float)(pix & 63) - 1.0f + (float)(k % 3) + dx;
    py[idx] = yy;
    px[idx] = xv;
    mk[idx] = 1.0f / (1.0f + __expf(-m));
}

// ---------------- kernel 6a: sampler — materialize A in fragment order ---------------
// 4608 blocks x 4 waves = 18432 waves; wave = (mf, k2); 8 independent blend+store steps.
// No LDS, no barriers, no MFMA. XCD-swizzled so each XCD samples exactly one batch.
__launch_bounds__(256, 4)
__global__ void sample_a(const unsigned short* __restrict__ xn,
                         const float* __restrict__ pyA,
                         const float* __restrict__ pxA,
                         const float* __restrict__ mkA,
                         unsigned short* __restrict__ am) {
    int bid = blockIdx.x;                       // 4608
    int lid = (bid & 7)*576 + (bid >> 3);       // XCD k -> one batch's frags
    int t = threadIdx.x, wv = t >> 6, l = t & 63, g = l >> 4, l15 = l & 15;
    int wg = lid*4 + wv;                        // 0..18431
    int mf = wg / 9, k2 = wg - 9*mf;
    int pixg = mf*16 + l15;
    int b = pixg >> 12, pix = pixg & 4095;
    const char* xc = (const char*)(xn + (size_t)b*NPIX*NC);
    int ci = ((b*9 + k2) << 12) + pix;
    float py = pyA[ci], px = pxA[ci], m = mkA[ci];

    float y0f = floorf(py), x0f = floorf(px);
    float ly = py - y0f, lx = px - x0f;
    int iy0 = (int)y0f, ix0 = (int)x0f;
    int iy1 = iy0 + 1,  ix1 = ix0 + 1;
    bool vy0 = (iy0 >= 0) & (iy0 < HH);
    bool vy1 = (iy1 >= 0) & (iy1 < HH);
    bool vx0 = (ix0 >= 0) & (ix0 < WW);
    bool vx1 = (ix1 >= 0) & (ix1 < WW);
    float wy0 = (1.f - ly) * m, wy1 = ly * m;
    float cw0 = (vy0 & vx0) ? wy0 * (1.f - lx) : 0.f;
    float cw1 = (vy0 & vx1) ? wy0 * lx         : 0.f;
    float cw2 = (vy1 & vx0) ? wy1 * (1.f - lx) : 0.f;
    float cw3 = (vy1 & vx1) ? wy1 * lx         : 0.f;
    int cy0 = min(max(iy0,0),HH-1), cy1 = min(max(iy1,0),HH-1);
    int cx0 = min(max(ix0,0),WW-1), cx1 = min(max(ix1,0),WW-1);
    unsigned co0 = (unsigned)(((cy0*WW + cx0)*NC + g*8) * 2);
    unsigned co1 = (unsigned)(((cy0*WW + cx1)*NC + g*8) * 2);
    unsigned co2 = (unsigned)(((cy1*WW + cx0)*NC + g*8) * 2);
    unsigned co3 = (unsigned)(((cy1*WW + cx1)*NC + g*8) * 2);

    unsigned short* dst = am + ((size_t)(k2*8)*NMF + mf)*512 + l*8;
#pragma unroll
    for (int cc = 0; cc < 8; ++cc) {
        unsigned cb = (unsigned)cc * 64u;
        bf16x8 c0 = *(const bf16x8*)(xc + co0 + cb);
        bf16x8 c1 = *(const bf16x8*)(xc + co1 + cb);
        bf16x8 c2 = *(const bf16x8*)(xc + co2 + cb);
        bf16x8 c3 = *(const bf16x8*)(xc + co3 + cb);
        bf16x8 af = blend4(c0, c1, c2, c3, cw0, cw1, cw2, cw3);
        *(bf16x8*)(dst + (size_t)cc*NMF*512) = af;
    }
}

// ---------------- kernel 6b: GEMM C = A(32768x2304) * W(2304x256) -------------------
// m97 pattern: 512 blocks (128x128 tile), 4 waves (2x2), BK=32, dbuf LDS via
// global_load_lds width 16, one __syncthreads per K-step.
__launch_bounds__(256, 2)
__global__ void gemm_a(const unsigned short* __restrict__ am,
                       const unsigned short* __restrict__ wpack,
                       const float* __restrict__ bias,
                       float* __restrict__ out) {
    __shared__ unsigned short lds[2][8192];     // per buf: A 8KB + B 8KB
    int bid = blockIdx.x;
    int lid = (bid & 7)*64 + (bid >> 3);        // XCD swizzle (512 % 8 == 0)
    int mt = lid >> 1, nh = lid & 1;            // mt 0..255 (128 pixels), N-half
    int t = threadIdx.x, l = t & 63, g = l >> 4, l15 = l & 15;
    int wv = t >> 6, wm = wv >> 1, wn = wv & 1; // 2x2 wave grid

    f32x4 acc[4][4];
#pragma unroll
    for (int i = 0; i < 4; ++i)
#pragma unroll
        for (int j = 0; j < 4; ++j) acc[i][j] = f32x4{0.f,0.f,0.f,0.f};

#define GLDS(gp, lp)                                                        \
    __builtin_amdgcn_global_load_lds(                                       \
        (const __attribute__((address_space(1))) unsigned int*)(gp),        \
        (__attribute__((address_space(3))) unsigned int*)(lp), 16, 0, 0)

    auto stage = [&](int buf, int kc) {
        const unsigned short* ga = am    + ((size_t)kc*NMF + mt*8)*512 + t*8;
        const unsigned short* gb = wpack + ((size_t)kc*16 + nh*8)*512 + t*8;
        unsigned short* la = &lds[buf][0]    + t*8;
        unsigned short* lb = &lds[buf][4096] + t*8;
        GLDS(ga,        la);
        GLDS(ga + 2048, la + 2048);
        GLDS(gb,        lb);
        GLDS(gb + 2048, lb + 2048);
    };

    stage(0, 0);
    __syncthreads();
    for (int kc = 0; kc < NKC; ++kc) {
        int buf = kc & 1;
        if (kc < NKC-1) stage(buf ^ 1, kc + 1);
        const bf16x8* A  = (const bf16x8*)&lds[buf][0];
        const bf16x8* Bf = (const bf16x8*)&lds[buf][4096];
        bf16x8 a[4], bq[4];
#pragma unroll
        for (int i = 0; i < 4; ++i) a[i]  = A [(wm*4 + i)*64 + l];
#pragma unroll
        for (int j = 0; j < 4; ++j) bq[j] = Bf[(wn*4 + j)*64 + l];
#pragma unroll
        for (int i = 0; i < 4; ++i)
#pragma unroll
            for (int j = 0; j < 4; ++j)
                acc[i][j] = __builtin_amdgcn_mfma_f32_16x16x32_bf16(a[i], bq[j], acc[i][j], 0, 0, 0);
        __syncthreads();
    }
#undef GLDS

    int b  = mt >> 5;
    int pb = (mt & 31)*128 + wm*64 + 4*g;
#pragma unroll
    for (int i = 0; i < 4; ++i)
#pragma unroll
        for (int j = 0; j < 4; ++j) {
            int o = nh*128 + wn*64 + j*16 + l15;
            f32x4 r = acc[i][j] + bias[o];
            *(f32x4*)(out + ((size_t)(b*NO + o))*NPIX + pb + i*16) = r;
        }
}

// ---------------- fallback: round-1 fused dcn (used when ws too small) ---------------
__launch_bounds__(256, 2)
__global__ void dcn_fused(const unsigned short* __restrict__ xn,
                          const unsigned short* __restrict__ wpack,
                          const float* __restrict__ pyA,
                          const float* __restrict__ pxA,
                          const float* __restrict__ mkA,
                          const float* __restrict__ bias,
                          float* __restrict__ out) {
    __shared__ unsigned short lds[2][8192];
    int blk = blockIdx.x;
    int mt = blk & 63, b = blk >> 6;
    int t = threadIdx.x, wv = t >> 6, l = t & 63, g = l >> 4;
    int pixm = mt*64 + wv*16 + (l & 15);

    f32x4 acc[16];
#pragma unroll
    for (int i = 0; i < 16; ++i) acc[i] = f32x4{0.f,0.f,0.f,0.f};

    const unsigned short* xb = xn + (size_t)b*NPIX*NC;

#define STAGE(bi, kcs) do {                                                            \
        const unsigned short* _gs = wpack + (size_t)(kcs)*8192 + wv*2048 + l*8;        \
        _Pragma("unroll")                                                              \
        for (int _i = 0; _i < 4; ++_i) {                                               \
            __builtin_amdgcn_global_load_lds(                                          \
                (const __attribute__((address_space(1))) unsigned int*)(_gs + _i*512), \
                (__attribute__((address_space(3))) unsigned int*)(&lds[bi][wv*2048 + _i*512]), \
                16, 0, 0);                                                             \
        }                                                                              \
    } while (0)

    float cw0 = 0.f, cw1 = 0.f, cw2 = 0.f, cw3 = 0.f;
    unsigned ca0 = 0, ca1 = 0, ca2 = 0, ca3 = 0;

    STAGE(0, 0);
    __syncthreads();
    int buf = 0;
    for (int kc = 0; kc < NKC; ++kc) {
        int k2 = kc >> 3, cc = kc & 7;
        if (cc == 0) {
            int ci = ((b*9 + k2) << 12) + pixm;
            float py = pyA[ci], px = pxA[ci], m = mkA[ci];
            float y0f = floorf(py), x0f = floorf(px);
            float ly = py - y0f, lx = px - x0f;
            int iy0 = (int)y0f, ix0 = (int)x0f;
            int iy1 = iy0 + 1,  ix1 = ix0 + 1;
            bool vy0 = (iy0 >= 0) & (iy0 < HH);
            bool vy1 = (iy1 >= 0) & (iy1 < HH);
            bool vx0 = (ix0 >= 0) & (ix0 < WW);
            bool vx1 = (ix1 >= 0) & (ix1 < WW);
            float wy0 = (1.f - ly) * m, wy1 = ly * m;
            cw0 = (vy0 & vx0) ? wy0 * (1.f - lx) : 0.f;
            cw1 = (vy0 & vx1) ? wy0 * lx         : 0.f;
            cw2 = (vy1 & vx0) ? wy1 * (1.f - lx) : 0.f;
            cw3 = (vy1 & vx1) ? wy1 * lx         : 0.f;
            int cy0 = min(max(iy0, 0), HH-1), cy1 = min(max(iy1, 0), HH-1);
            int cx0 = min(max(ix0, 0), WW-1), cx1 = min(max(ix1, 0), WW-1);
            ca0 = (unsigned)(((cy0*WW + cx0)*NC + g*8) * 2);
            ca1 = (unsigned)(((cy0*WW + cx1)*NC + g*8) * 2);
            ca2 = (unsigned)(((cy1*WW + cx0)*NC + g*8) * 2);
            ca3 = (unsigned)(((cy1*WW + cx1)*NC + g*8) * 2);
        }
        if (kc < NKC-1) STAGE(buf ^ 1, kc + 1);

        unsigned co = (unsigned)cc * 64u;
        const char* xcc = (const char*)xb;
        bf16x8 v00 = *(const bf16x8*)(xcc + ca0 + co);
        bf16x8 v01 = *(const bf16x8*)(xcc + ca1 + co);
        bf16x8 v10 = *(const bf16x8*)(xcc + ca2 + co);
        bf16x8 v11 = *(const bf16x8*)(xcc + ca3 + co);
        bf16x8 a = blend4(v00, v01, v10, v11, cw0, cw1, cw2, cw3);
        const bf16x8* bl = (const bf16x8*)&lds[buf][0];
#pragma unroll
        for (int nt = 0; nt < 16; ++nt)
            acc[nt] = __builtin_amdgcn_mfma_f32_16x16x32_bf16(a, bl[nt*64 + l], acc[nt], 0, 0, 0);
        __syncthreads();
        buf ^= 1;
    }
#undef STAGE

    int pm = mt*64 + wv*16 + 4*g;
#pragma unroll
    for (int nt = 0; nt < 16; ++nt) {
        int o = nt*16 + (l & 15);
        float bv = bias[o];
        f32x4 r = acc[nt] + bv;
        *(f32x4*)(out + ((size_t)(b*NO + o))*NPIX + pm) = r;
    }
}

extern "C" void kernel_launch(void* const* d_in, const int* in_sizes, int n_in,
                              void* d_out, int out_size, void* d_ws, size_t ws_size,
                              hipStream_t stream) {
    const float* x      = (const float*)d_in[0];
    const float* weight = (const float*)d_in[1];
    const float* bias   = (const float*)d_in[2];
    const float* w_off  = (const float*)d_in[3];
    const float* b_off  = (const float*)d_in[4];
    float* out = (float*)d_out;
    char* ws = (char*)d_ws;

    unsigned short* xn  = (unsigned short*)(ws + XN_OFF);
    unsigned short* wp  = (unsigned short*)(ws + WP_OFF);
    unsigned short* wpo = (unsigned short*)(ws + WPO_OFF);
    float* om = (float*)(ws + OM_OFF);
    float* py = (float*)(ws + PY_OFF);
    float* px = (float*)(ws + PX_OFF);
    float* mk = (float*)(ws + MK_OFF);
    unsigned short* am  = (unsigned short*)(ws + AM_OFF);

    pack_x  <<<2048, 256, 0, stream>>>(x, xn);
    pack_w  <<<KTOT*NO/256,  256, 0, stream>>>(weight, wp);
    pack_wo <<<KTOT*32/256,  256, 0, stream>>>(w_off, wpo);
    off_conv<<<1024, 256, 0, stream>>>(xn, wpo, om);
    coords_k<<<NB*9*NPIX/256, 256, 0, stream>>>(om, b_off, py, px, mk);

    if (ws_size >= (size_t)AM_OFF + AM_SZ) {
        sample_a<<<4608, 256, 0, stream>>>(xn, py, px, mk, am);
        gemm_a  <<<512,  256, 0, stream>>>(am, wp, bias, out);
    } else {
        dcn_fused<<<512, 256, 0, stream>>>(xn, wp, py, px, mk, bias, out);
    }
}